// Round 1
// baseline (432.337 us; speedup 1.0000x reference)
//
#include <hip/hip_runtime.h>
#include <hip/hip_bf16.h>

#define H      2048
#define IN     1408
#define NE     8
#define NTOK   2048
#define NSLOT  (NTOK*2)
#define BM     64
#define BN     64
#define BK     64

typedef __attribute__((ext_vector_type(8))) short bf16x8;
typedef __attribute__((ext_vector_type(4))) float f32x4;

__device__ __forceinline__ ushort f2bf(float f) {
  unsigned u = __float_as_uint(f);
  return (ushort)((u + 0x7FFFu + ((u >> 16) & 1u)) >> 16);
}
__device__ __forceinline__ unsigned pack2(float lo, float hi) {
  return (unsigned)f2bf(lo) | ((unsigned)f2bf(hi) << 16);
}

// ---------------- init: zero final output region + counts ----------------
__global__ void init_kernel(float4* __restrict__ outF, int* __restrict__ counts) {
  size_t i = (size_t)blockIdx.x * blockDim.x + threadIdx.x;
  size_t stride = (size_t)gridDim.x * blockDim.x;
  size_t n4 = (size_t)NTOK * H / 4;
  float4 z = make_float4(0.f, 0.f, 0.f, 0.f);
  for (size_t j = i; j < n4; j += stride) outF[j] = z;
  if (i < NE) counts[i] = 0;
}

// ---------------- router: logits, top-2, weights ----------------
__global__ __launch_bounds__(256) void router_kernel(
    const float* __restrict__ x, const float* __restrict__ gw,
    float* __restrict__ logits_out, int* __restrict__ counts,
    int* __restrict__ topk_idx, float* __restrict__ topk_w) {
  int n = blockIdx.x;
  __shared__ float xs[H];
  __shared__ float red[4];
  __shared__ float lg[NE];
  const float* xr = x + (size_t)n * H;
  for (int i = threadIdx.x; i < H / 4; i += 256)
    ((float4*)xs)[i] = ((const float4*)xr)[i];
  __syncthreads();
  for (int e = 0; e < NE; ++e) {
    float p = 0.f;
    const float* w = gw + (size_t)e * H;
    for (int i = threadIdx.x; i < H; i += 256) p += xs[i] * w[i];
    for (int o = 32; o; o >>= 1) p += __shfl_down(p, o);
    if ((threadIdx.x & 63) == 0) red[threadIdx.x >> 6] = p;
    __syncthreads();
    if (threadIdx.x == 0) lg[e] = red[0] + red[1] + red[2] + red[3];
    __syncthreads();
  }
  if (threadIdx.x < NE) logits_out[(size_t)n * NE + threadIdx.x] = lg[threadIdx.x];
  if (threadIdx.x == 0) {
    int i1 = 0; float v1 = lg[0];
    for (int e = 1; e < NE; ++e) if (lg[e] > v1) { v1 = lg[e]; i1 = e; }
    int i2 = -1; float v2 = -1e30f;
    for (int e = 0; e < NE; ++e) if (e != i1 && lg[e] > v2) { v2 = lg[e]; i2 = e; }
    float ed = __expf(v2 - v1);          // <= 1
    float w1 = 1.f / (1.f + ed);
    float w2 = ed / (1.f + ed);
    topk_idx[n * 2 + 0] = i1; topk_idx[n * 2 + 1] = i2;
    topk_w[n * 2 + 0] = w1;  topk_w[n * 2 + 1] = w2;
    atomicAdd(&counts[i1], 1);
    atomicAdd(&counts[i2], 1);
  }
}

// ---------------- scan (8 experts) ----------------
__global__ void scan_kernel(const int* __restrict__ counts,
                            int* __restrict__ offsets, int* __restrict__ cursors) {
  if (threadIdx.x == 0) {
    int s = 0;
    for (int e = 0; e < NE; ++e) { offsets[e] = s; cursors[e] = s; s += counts[e]; }
  }
}

// ---------------- scatter tokens to expert slots ----------------
__global__ void scatter_kernel(const int* __restrict__ topk_idx,
                               const float* __restrict__ topk_w,
                               int* __restrict__ cursors,
                               int* __restrict__ slot_token, float* __restrict__ slot_w) {
  int n = blockIdx.x * 256 + threadIdx.x;
  if (n < NTOK) {
    for (int k = 0; k < 2; ++k) {
      int e = topk_idx[n * 2 + k];
      int s = atomicAdd(&cursors[e], 1);
      slot_token[s] = n;
      slot_w[s] = topk_w[n * 2 + k];
    }
  }
}

// ---------------- LDS staging helpers (XOR-swizzled, 16B slots) ----------------
// LDS tile: [64 rows][64 bf16] = row stride 128B = 8 slots of 16B; slot ^= (row&7)
__device__ __forceinline__ void stage_f32(ushort* lds, const float* src, bool valid,
                                          int row, int q) {
  float4 a0, a1, a2, a3;
  if (valid) {
    const float4* s = (const float4*)(src + 16 * q);
    a0 = s[0]; a1 = s[1]; a2 = s[2]; a3 = s[3];
  } else {
    a0 = a1 = a2 = a3 = make_float4(0.f, 0.f, 0.f, 0.f);
  }
  uint4 p0, p1;
  p0.x = pack2(a0.x, a0.y); p0.y = pack2(a0.z, a0.w);
  p0.z = pack2(a1.x, a1.y); p0.w = pack2(a1.z, a1.w);
  p1.x = pack2(a2.x, a2.y); p1.y = pack2(a2.z, a2.w);
  p1.z = pack2(a3.x, a3.y); p1.w = pack2(a3.z, a3.w);
  uint4* base = (uint4*)((char*)lds + row * 128);
  base[(2 * q) ^ (row & 7)]     = p0;
  base[(2 * q + 1) ^ (row & 7)] = p1;
}

__device__ __forceinline__ void stage_bf16(ushort* lds, const ushort* src, bool valid,
                                           int row, int q) {
  uint4 p0 = {0u,0u,0u,0u}, p1 = {0u,0u,0u,0u};
  if (valid) {
    const uint4* s = (const uint4*)(src + 16 * q);
    p0 = s[0]; p1 = s[1];
  }
  uint4* base = (uint4*)((char*)lds + row * 128);
  base[(2 * q) ^ (row & 7)]     = p0;
  base[(2 * q + 1) ^ (row & 7)] = p1;
}

__device__ __forceinline__ bf16x8 read_frag(const ushort* lds, int row, int kk, int lane) {
  int slot = (kk * 4 + (lane >> 4)) ^ (row & 7);
  return *(const bf16x8*)((const char*)lds + row * 128 + slot * 16);
}

// ---------------- GEMM1: act = silu(x@Wg^T) * (x@Wu^T), bf16 out ----------------
__global__ __launch_bounds__(256) void gemm1_kernel(
    const float* __restrict__ x, const float* __restrict__ gup,
    const int* __restrict__ offsets, const int* __restrict__ counts,
    const int* __restrict__ slot_token, ushort* __restrict__ act) {
  int e = blockIdx.z, mt = blockIdx.y, nt = blockIdx.x;
  int cnt = counts[e];
  if (mt * BM >= cnt) return;
  int off = offsets[e];
  __shared__ ushort As[BM * BK], Bg[BN * BK], Bu[BN * BK];
  int tid = threadIdx.x;
  int lane = tid & 63, wid = tid >> 6;
  int wm = (wid >> 1) * 32, wn = (wid & 1) * 32;
  int ar = tid >> 2, aq = tid & 3;
  bool avalid = (mt * BM + ar) < cnt;
  const float* arow = x;
  if (avalid) arow = x + (size_t)slot_token[off + mt * BM + ar] * H;
  const float* grow = gup + ((size_t)e * (2 * IN) + nt * BN + ar) * H;
  const float* urow = gup + ((size_t)e * (2 * IN) + IN + nt * BN + ar) * H;

  f32x4 zz = {0.f, 0.f, 0.f, 0.f};
  f32x4 accg[2][2], accu[2][2];
  for (int mi = 0; mi < 2; ++mi) for (int ni = 0; ni < 2; ++ni) { accg[mi][ni] = zz; accu[mi][ni] = zz; }

  for (int k0 = 0; k0 < H; k0 += BK) {
    stage_f32(As, arow + k0, avalid, ar, aq);
    stage_f32(Bg, grow + k0, true, ar, aq);
    stage_f32(Bu, urow + k0, true, ar, aq);
    __syncthreads();
#pragma unroll
    for (int kk = 0; kk < 2; ++kk) {
      bf16x8 af[2], bg2[2], bu2[2];
#pragma unroll
      for (int i = 0; i < 2; ++i) {
        af[i]  = read_frag(As, wm + i * 16 + (lane & 15), kk, lane);
        bg2[i] = read_frag(Bg, wn + i * 16 + (lane & 15), kk, lane);
        bu2[i] = read_frag(Bu, wn + i * 16 + (lane & 15), kk, lane);
      }
#pragma unroll
      for (int mi = 0; mi < 2; ++mi)
#pragma unroll
        for (int ni = 0; ni < 2; ++ni) {
          accg[mi][ni] = __builtin_amdgcn_mfma_f32_16x16x32_bf16(af[mi], bg2[ni], accg[mi][ni], 0, 0, 0);
          accu[mi][ni] = __builtin_amdgcn_mfma_f32_16x16x32_bf16(af[mi], bu2[ni], accu[mi][ni], 0, 0, 0);
        }
    }
    __syncthreads();
  }
  // epilogue: C[row=(lane>>4)*4+r][col=lane&15]
  int rb = mt * BM + wm + ((lane >> 4) << 2);
#pragma unroll
  for (int mi = 0; mi < 2; ++mi) {
#pragma unroll
    for (int r = 0; r < 4; ++r) {
      int mrow = rb + mi * 16 + r;
      if (mrow < cnt) {
        size_t rowo = (size_t)(off + mrow) * IN;
#pragma unroll
        for (int ni = 0; ni < 2; ++ni) {
          float g = accg[mi][ni][r], u = accu[mi][ni][r];
          float a = g / (1.f + __expf(-g)) * u;
          act[rowo + nt * BN + wn + ni * 16 + (lane & 15)] = f2bf(a);
        }
      }
    }
  }
}

// ---------------- GEMM2: out += w * (act @ Wd^T) ----------------
__global__ __launch_bounds__(256) void gemm2_kernel(
    const ushort* __restrict__ act, const float* __restrict__ down,
    const int* __restrict__ offsets, const int* __restrict__ counts,
    const int* __restrict__ slot_token, const float* __restrict__ slot_w,
    float* __restrict__ outF) {
  int e = blockIdx.z, mt = blockIdx.y, nt = blockIdx.x;
  int cnt = counts[e];
  if (mt * BM >= cnt) return;
  int off = offsets[e];
  __shared__ ushort As[BM * BK], Bs[BN * BK];
  int tid = threadIdx.x;
  int lane = tid & 63, wid = tid >> 6;
  int wm = (wid >> 1) * 32, wn = (wid & 1) * 32;
  int ar = tid >> 2, aq = tid & 3;
  bool avalid = (mt * BM + ar) < cnt;
  const ushort* arow = act + (size_t)(off + mt * BM + (avalid ? ar : 0)) * IN;
  const float* brow = down + ((size_t)e * H + nt * BN + ar) * IN;

  f32x4 zz = {0.f, 0.f, 0.f, 0.f};
  f32x4 acc[2][2];
  for (int mi = 0; mi < 2; ++mi) for (int ni = 0; ni < 2; ++ni) acc[mi][ni] = zz;

  for (int k0 = 0; k0 < IN; k0 += BK) {
    stage_bf16(As, arow + k0, avalid, ar, aq);
    stage_f32(Bs, brow + k0, true, ar, aq);
    __syncthreads();
#pragma unroll
    for (int kk = 0; kk < 2; ++kk) {
      bf16x8 af[2], bf2[2];
#pragma unroll
      for (int i = 0; i < 2; ++i) {
        af[i]  = read_frag(As, wm + i * 16 + (lane & 15), kk, lane);
        bf2[i] = read_frag(Bs, wn + i * 16 + (lane & 15), kk, lane);
      }
#pragma unroll
      for (int mi = 0; mi < 2; ++mi)
#pragma unroll
        for (int ni = 0; ni < 2; ++ni)
          acc[mi][ni] = __builtin_amdgcn_mfma_f32_16x16x32_bf16(af[mi], bf2[ni], acc[mi][ni], 0, 0, 0);
    }
    __syncthreads();
  }
  int rb = mt * BM + wm + ((lane >> 4) << 2);
#pragma unroll
  for (int mi = 0; mi < 2; ++mi) {
#pragma unroll
    for (int r = 0; r < 4; ++r) {
      int mrow = rb + mi * 16 + r;
      if (mrow < cnt) {
        int slot = off + mrow;
        int token = slot_token[slot];
        float w = slot_w[slot];
#pragma unroll
        for (int ni = 0; ni < 2; ++ni)
          atomicAdd(&outF[(size_t)token * H + nt * BN + wn + ni * 16 + (lane & 15)],
                    w * acc[mi][ni][r]);
      }
    }
  }
}

extern "C" void kernel_launch(void* const* d_in, const int* in_sizes, int n_in,
                              void* d_out, int out_size, void* d_ws, size_t ws_size,
                              hipStream_t stream) {
  const float* x    = (const float*)d_in[0];
  const float* gw   = (const float*)d_in[1];
  const float* gup  = (const float*)d_in[2];
  const float* down = (const float*)d_in[3];
  float* outF   = (float*)d_out;                    // [NTOK, H]
  float* logits = outF + (size_t)NTOK * H;          // [NTOK, NE]

  char* ws = (char*)d_ws;
  int*   counts     = (int*)(ws + 0);
  int*   offsets    = (int*)(ws + 32);
  int*   cursors    = (int*)(ws + 64);
  int*   topk_idx   = (int*)(ws + 128);                 // NTOK*2 ints
  float* topk_w     = (float*)(ws + 128 + 16384);       // NTOK*2 floats
  int*   slot_token = (int*)(ws + 128 + 32768);         // NSLOT ints
  float* slot_w     = (float*)(ws + 128 + 49152);       // NSLOT floats
  ushort* act       = (ushort*)(ws + 65792);            // NSLOT*IN bf16 (~11.5 MB)

  init_kernel<<<2048, 256, 0, stream>>>((float4*)outF, counts);
  router_kernel<<<NTOK, 256, 0, stream>>>(x, gw, logits, counts, topk_idx, topk_w);
  scan_kernel<<<1, 64, 0, stream>>>(counts, offsets, cursors);
  scatter_kernel<<<NTOK / 256, 256, 0, stream>>>(topk_idx, topk_w, cursors, slot_token, slot_w);
  gemm1_kernel<<<dim3(IN / BN, NTOK / BM, NE), 256, 0, stream>>>(x, gup, offsets, counts, slot_token, act);
  gemm2_kernel<<<dim3(H / BN, NTOK / BM, NE), 256, 0, stream>>>(act, down, offsets, counts, slot_token, slot_w, outF);
}

// Round 2
// 330.143 us; speedup vs baseline: 1.3095x; 1.3095x over previous
//
#include <hip/hip_runtime.h>
#include <hip/hip_bf16.h>

#define H      2048
#define IN     1408
#define NE     8
#define NTOK   2048
#define NSLOT  (NTOK*2)

typedef __attribute__((ext_vector_type(8))) short bf16x8;
typedef __attribute__((ext_vector_type(4))) float f32x4;

__device__ __forceinline__ ushort f2bf(float f) {
  unsigned u = __float_as_uint(f);
  return (ushort)((u + 0x7FFFu + ((u >> 16) & 1u)) >> 16);
}
__device__ __forceinline__ unsigned pack2(float lo, float hi) {
  return (unsigned)f2bf(lo) | ((unsigned)f2bf(hi) << 16);
}

#define GLOAD_LDS16(gp, lp)                                                     \
  __builtin_amdgcn_global_load_lds(                                             \
      (const __attribute__((address_space(1))) void*)(gp),                      \
      (__attribute__((address_space(3))) void*)(lp), 16, 0, 0)

// ---------------- init: zero final output region + counts ----------------
__global__ void init_kernel(float4* __restrict__ outF, int* __restrict__ counts) {
  size_t i = (size_t)blockIdx.x * blockDim.x + threadIdx.x;
  size_t stride = (size_t)gridDim.x * blockDim.x;
  size_t n4 = (size_t)NTOK * H / 4;
  float4 z = make_float4(0.f, 0.f, 0.f, 0.f);
  for (size_t j = i; j < n4; j += stride) outF[j] = z;
  if (i < NE) counts[i] = 0;
}

// ---------------- f32 -> bf16 convert ----------------
__global__ __launch_bounds__(256) void cvt_kernel(const float4* __restrict__ src,
                                                  uint2* __restrict__ dst, int n4) {
  int i = blockIdx.x * 256 + threadIdx.x;
  int stride = gridDim.x * 256;
  for (; i < n4; i += stride) {
    float4 v = src[i];
    uint2 o; o.x = pack2(v.x, v.y); o.y = pack2(v.z, v.w);
    dst[i] = o;
  }
}

// ---------------- router: logits, top-2, weights ----------------
__global__ __launch_bounds__(256) void router_kernel(
    const float* __restrict__ x, const float* __restrict__ gw,
    float* __restrict__ logits_out, int* __restrict__ counts,
    int* __restrict__ topk_idx, float* __restrict__ topk_w) {
  int n = blockIdx.x;
  __shared__ float xs[H];
  __shared__ float red[4];
  __shared__ float lg[NE];
  const float* xr = x + (size_t)n * H;
  for (int i = threadIdx.x; i < H / 4; i += 256)
    ((float4*)xs)[i] = ((const float4*)xr)[i];
  __syncthreads();
  for (int e = 0; e < NE; ++e) {
    float p = 0.f;
    const float* w = gw + (size_t)e * H;
    for (int i = threadIdx.x; i < H; i += 256) p += xs[i] * w[i];
    for (int o = 32; o; o >>= 1) p += __shfl_down(p, o);
    if ((threadIdx.x & 63) == 0) red[threadIdx.x >> 6] = p;
    __syncthreads();
    if (threadIdx.x == 0) lg[e] = red[0] + red[1] + red[2] + red[3];
    __syncthreads();
  }
  if (threadIdx.x < NE) logits_out[(size_t)n * NE + threadIdx.x] = lg[threadIdx.x];
  if (threadIdx.x == 0) {
    int i1 = 0; float v1 = lg[0];
    for (int e = 1; e < NE; ++e) if (lg[e] > v1) { v1 = lg[e]; i1 = e; }
    int i2 = -1; float v2 = -1e30f;
    for (int e = 0; e < NE; ++e) if (e != i1 && lg[e] > v2) { v2 = lg[e]; i2 = e; }
    float ed = __expf(v2 - v1);          // <= 1
    float w1 = 1.f / (1.f + ed);
    float w2 = ed / (1.f + ed);
    topk_idx[n * 2 + 0] = i1; topk_idx[n * 2 + 1] = i2;
    topk_w[n * 2 + 0] = w1;  topk_w[n * 2 + 1] = w2;
    atomicAdd(&counts[i1], 1);
    atomicAdd(&counts[i2], 1);
  }
}

// ---------------- scan (8 experts) ----------------
__global__ void scan_kernel(const int* __restrict__ counts,
                            int* __restrict__ offsets, int* __restrict__ cursors) {
  if (threadIdx.x == 0) {
    int s = 0;
    for (int e = 0; e < NE; ++e) { offsets[e] = s; cursors[e] = s; s += counts[e]; }
  }
}

// ---------------- scatter tokens to expert slots ----------------
__global__ void scatter_kernel(const int* __restrict__ topk_idx,
                               const float* __restrict__ topk_w,
                               int* __restrict__ cursors,
                               int* __restrict__ slot_token, float* __restrict__ slot_w) {
  int n = blockIdx.x * 256 + threadIdx.x;
  if (n < NTOK) {
    for (int k = 0; k < 2; ++k) {
      int e = topk_idx[n * 2 + k];
      int s = atomicAdd(&cursors[e], 1);
      slot_token[s] = n;
      slot_w[s] = topk_w[n * 2 + k];
    }
  }
}

// Fragment read from linear LDS tile [rows][64 bf16] with slot-XOR swizzle.
// Data for logical slot s of row r lives at physical slot s^(r&7) (the global
// source was pre-permuted the same way -> read gets the right bytes, and the
// XOR spreads 16 same-column lanes across 8 banks-groups (2-way = free).
__device__ __forceinline__ bf16x8 read_frag(const ushort* lds, int row, int kk, int lane) {
  int slot = (kk * 4 + (lane >> 4)) ^ (row & 7);
  return *(const bf16x8*)(lds + row * 64 + slot * 8);
}

// ---------------- GEMM1: act = silu(x@Wg^T) * (x@Wu^T), bf16 ----------------
// tile: 128 slots x 64 cols (of both gate and up), BK=64, 4 waves (32 rows each)
__global__ __launch_bounds__(256) void gemm1_kernel(
    const ushort* __restrict__ xb, const ushort* __restrict__ gupb,
    const int* __restrict__ offsets, const int* __restrict__ counts,
    const int* __restrict__ slot_token, ushort* __restrict__ act) {
  int e = blockIdx.z, mt = blockIdx.y, nt = blockIdx.x;
  int cnt = counts[e];
  if (mt * 128 >= cnt) return;
  int off = offsets[e];
  __shared__ ushort As[128 * 64], Bg[64 * 64], Bu[64 * 64];
  int tid = threadIdx.x, lane = tid & 63, wid = tid >> 6;
  int q = tid & 7;

  // per-thread staging sources (16B each), source-slot XOR pre-applied
  const ushort* aSrc[4];
#pragma unroll
  for (int it = 0; it < 4; ++it) {
    int row = (it * 256 + tid) >> 3;               // 0..127
    int grow = mt * 128 + row; if (grow >= cnt) grow = cnt - 1;
    int token = slot_token[off + grow];
    aSrc[it] = xb + (size_t)token * H + (size_t)((q ^ (row & 7)) * 8);
  }
  const ushort *gSrc[2], *uSrc[2];
#pragma unroll
  for (int it = 0; it < 2; ++it) {
    int row = (it * 256 + tid) >> 3;               // 0..63
    gSrc[it] = gupb + ((size_t)e * (2 * IN) + nt * 64 + row) * H + (size_t)((q ^ (row & 7)) * 8);
    uSrc[it] = gupb + ((size_t)e * (2 * IN) + IN + nt * 64 + row) * H + (size_t)((q ^ (row & 7)) * 8);
  }

  f32x4 zz = {0.f, 0.f, 0.f, 0.f};
  f32x4 accg[2][4], accu[2][4];
#pragma unroll
  for (int mi = 0; mi < 2; ++mi)
#pragma unroll
    for (int ni = 0; ni < 4; ++ni) { accg[mi][ni] = zz; accu[mi][ni] = zz; }

  for (int k0 = 0; k0 < H; k0 += 64) {
#pragma unroll
    for (int it = 0; it < 4; ++it)
      GLOAD_LDS16(aSrc[it] + k0, As + it * 2048 + tid * 8);
#pragma unroll
    for (int it = 0; it < 2; ++it) {
      GLOAD_LDS16(gSrc[it] + k0, Bg + it * 2048 + tid * 8);
      GLOAD_LDS16(uSrc[it] + k0, Bu + it * 2048 + tid * 8);
    }
    __syncthreads();
#pragma unroll
    for (int kk = 0; kk < 2; ++kk) {
      bf16x8 af[2], bg[4], bu[4];
#pragma unroll
      for (int mi = 0; mi < 2; ++mi)
        af[mi] = read_frag(As, wid * 32 + mi * 16 + (lane & 15), kk, lane);
#pragma unroll
      for (int ni = 0; ni < 4; ++ni) {
        bg[ni] = read_frag(Bg, ni * 16 + (lane & 15), kk, lane);
        bu[ni] = read_frag(Bu, ni * 16 + (lane & 15), kk, lane);
      }
#pragma unroll
      for (int mi = 0; mi < 2; ++mi)
#pragma unroll
        for (int ni = 0; ni < 4; ++ni) {
          accg[mi][ni] = __builtin_amdgcn_mfma_f32_16x16x32_bf16(af[mi], bg[ni], accg[mi][ni], 0, 0, 0);
          accu[mi][ni] = __builtin_amdgcn_mfma_f32_16x16x32_bf16(af[mi], bu[ni], accu[mi][ni], 0, 0, 0);
        }
    }
    __syncthreads();
  }
  // epilogue: C[row=(lane>>4)*4+r][col=lane&15]
  int rbase = mt * 128 + wid * 32 + ((lane >> 4) << 2);
  int cbase = nt * 64 + (lane & 15);
#pragma unroll
  for (int mi = 0; mi < 2; ++mi)
#pragma unroll
    for (int r = 0; r < 4; ++r) {
      int mrow = rbase + mi * 16 + r;
      if (mrow < cnt) {
        size_t rowo = (size_t)(off + mrow) * IN;
#pragma unroll
        for (int ni = 0; ni < 4; ++ni) {
          float g = accg[mi][ni][r], u = accu[mi][ni][r];
          float a = g / (1.f + __expf(-g)) * u;
          act[rowo + cbase + ni * 16] = f2bf(a);
        }
      }
    }
}

// ---------------- GEMM2: out += w * (act @ Wd^T) ----------------
__global__ __launch_bounds__(256) void gemm2_kernel(
    const ushort* __restrict__ act, const ushort* __restrict__ downb,
    const int* __restrict__ offsets, const int* __restrict__ counts,
    const int* __restrict__ slot_token, const float* __restrict__ slot_w,
    float* __restrict__ outF) {
  int e = blockIdx.z, mt = blockIdx.y, nt = blockIdx.x;
  int cnt = counts[e];
  if (mt * 128 >= cnt) return;
  int off = offsets[e];
  __shared__ ushort As[128 * 64], Bs[64 * 64];
  int tid = threadIdx.x, lane = tid & 63, wid = tid >> 6;
  int q = tid & 7;

  const ushort* aSrc[4];
#pragma unroll
  for (int it = 0; it < 4; ++it) {
    int row = (it * 256 + tid) >> 3;
    int grow = mt * 128 + row; if (grow >= cnt) grow = cnt - 1;
    aSrc[it] = act + (size_t)(off + grow) * IN + (size_t)((q ^ (row & 7)) * 8);
  }
  const ushort* bSrc[2];
#pragma unroll
  for (int it = 0; it < 2; ++it) {
    int row = (it * 256 + tid) >> 3;
    bSrc[it] = downb + ((size_t)e * H + nt * 64 + row) * IN + (size_t)((q ^ (row & 7)) * 8);
  }

  f32x4 zz = {0.f, 0.f, 0.f, 0.f};
  f32x4 acc[2][4];
#pragma unroll
  for (int mi = 0; mi < 2; ++mi)
#pragma unroll
    for (int ni = 0; ni < 4; ++ni) acc[mi][ni] = zz;

  for (int k0 = 0; k0 < IN; k0 += 64) {
#pragma unroll
    for (int it = 0; it < 4; ++it)
      GLOAD_LDS16(aSrc[it] + k0, As + it * 2048 + tid * 8);
#pragma unroll
    for (int it = 0; it < 2; ++it)
      GLOAD_LDS16(bSrc[it] + k0, Bs + it * 2048 + tid * 8);
    __syncthreads();
#pragma unroll
    for (int kk = 0; kk < 2; ++kk) {
      bf16x8 af[2], bf[4];
#pragma unroll
      for (int mi = 0; mi < 2; ++mi)
        af[mi] = read_frag(As, wid * 32 + mi * 16 + (lane & 15), kk, lane);
#pragma unroll
      for (int ni = 0; ni < 4; ++ni)
        bf[ni] = read_frag(Bs, ni * 16 + (lane & 15), kk, lane);
#pragma unroll
      for (int mi = 0; mi < 2; ++mi)
#pragma unroll
        for (int ni = 0; ni < 4; ++ni)
          acc[mi][ni] = __builtin_amdgcn_mfma_f32_16x16x32_bf16(af[mi], bf[ni], acc[mi][ni], 0, 0, 0);
    }
    __syncthreads();
  }
  int rbase = mt * 128 + wid * 32 + ((lane >> 4) << 2);
  int cbase = nt * 64 + (lane & 15);
#pragma unroll
  for (int mi = 0; mi < 2; ++mi)
#pragma unroll
    for (int r = 0; r < 4; ++r) {
      int mrow = rbase + mi * 16 + r;
      if (mrow < cnt) {
        int slot = off + mrow;
        int token = slot_token[slot];
        float w = slot_w[slot];
#pragma unroll
        for (int ni = 0; ni < 4; ++ni)
          atomicAdd(&outF[(size_t)token * H + cbase + ni * 16], w * acc[mi][ni][r]);
      }
    }
}

extern "C" void kernel_launch(void* const* d_in, const int* in_sizes, int n_in,
                              void* d_out, int out_size, void* d_ws, size_t ws_size,
                              hipStream_t stream) {
  const float* x    = (const float*)d_in[0];
  const float* gw   = (const float*)d_in[1];
  const float* gup  = (const float*)d_in[2];
  const float* down = (const float*)d_in[3];
  float* outF   = (float*)d_out;                    // [NTOK, H]
  float* logits = outF + (size_t)NTOK * H;          // [NTOK, NE]

  char* ws = (char*)d_ws;
  size_t o = 0;
  auto alloc = [&](size_t bytes) { char* p = ws + o; o = (o + bytes + 255) & ~(size_t)255; return p; };
  int*    counts     = (int*)alloc(32);
  int*    offsets    = (int*)alloc(32);
  int*    cursors    = (int*)alloc(32);
  int*    topk_idx   = (int*)alloc((size_t)NTOK * 2 * 4);
  float*  topk_w     = (float*)alloc((size_t)NTOK * 2 * 4);
  int*    slot_token = (int*)alloc((size_t)NSLOT * 4);
  float*  slot_w     = (float*)alloc((size_t)NSLOT * 4);
  ushort* xb         = (ushort*)alloc((size_t)NTOK * H * 2);
  ushort* act        = (ushort*)alloc((size_t)NSLOT * IN * 2);
  ushort* gupb       = (ushort*)alloc((size_t)NE * 2 * IN * H * 2);
  ushort* downb      = (ushort*)alloc((size_t)NE * H * IN * 2);
  if (o > ws_size) return;  // workspace too small -> visible failure

  init_kernel<<<2048, 256, 0, stream>>>((float4*)outF, counts);
  cvt_kernel<<<2048, 256, 0, stream>>>((const float4*)gup,  (uint2*)gupb,  NE * 2 * IN * H / 4);
  cvt_kernel<<<2048, 256, 0, stream>>>((const float4*)down, (uint2*)downb, NE * H * IN / 4);
  cvt_kernel<<<512,  256, 0, stream>>>((const float4*)x,    (uint2*)xb,    NTOK * H / 4);
  router_kernel<<<NTOK, 256, 0, stream>>>(x, gw, logits, counts, topk_idx, topk_w);
  scan_kernel<<<1, 64, 0, stream>>>(counts, offsets, cursors);
  scatter_kernel<<<NTOK / 256, 256, 0, stream>>>(topk_idx, topk_w, cursors, slot_token, slot_w);
  gemm1_kernel<<<dim3(IN / 64, NTOK / 128, NE), 256, 0, stream>>>(xb, gupb, offsets, counts, slot_token, act);
  gemm2_kernel<<<dim3(H / 64, NTOK / 128, NE), 256, 0, stream>>>(act, downb, offsets, counts, slot_token, slot_w, outF);
}